// Round 3
// baseline (15682.979 us; speedup 1.0000x reference)
//
#include <hip/hip_runtime.h>
#include <math.h>

#define NN 1600
#define MAXD 500
#define TS 500
#define NBATCH 4
#define GBLK 100
#define WAVES 4
#define RPW 4                 // rows per wave
#define RPB (WAVES * RPW)     // 16 rows per block
#define DT 0.05f

typedef unsigned long long u64;

// ---------------- workspace layout (floats) ----------------
// cnt : [0      , 800000)   N*MAXD delay-count weights
// Hc  : [800000 , 1600000)  circular history, head h (logical d -> (h+d)%MAXD)
// deT : byte offset 6400000, 2*NN u64 tagged exchange slots (val | epoch<<32)

#define AT_LOAD64(p)    __hip_atomic_load((p), __ATOMIC_RELAXED, __HIP_MEMORY_SCOPE_AGENT)
#define AT_STORE64(p,v) __hip_atomic_store((p), (v), __ATOMIC_RELAXED, __HIP_MEMORY_SCOPE_AGENT)

__device__ __forceinline__ float h_tf_dev(float a, float b, float d, float c) {
    float u   = a * c - b;
    float num = 1e-5f + fabsf(u);
    float den = 1e-5f * d + fabsf(1.0f - expf(-d * u));
    return num / (den + 1e-8f);
}

__global__ void cnt_kernel(const int* __restrict__ delays, float* __restrict__ cnt) {
    __shared__ int hist[MAXD];
    const int i = blockIdx.x;
    for (int d = threadIdx.x; d < MAXD; d += blockDim.x) hist[d] = 0;
    __syncthreads();
    const int* row = delays + (size_t)i * NN;
    for (int j = threadIdx.x; j < NN; j += blockDim.x) atomicAdd(&hist[row[j]], 1);
    __syncthreads();
    for (int d = threadIdx.x; d < MAXD; d += blockDim.x)
        cnt[(size_t)i * MAXD + d] = (float)hist[d];
}

__global__ void init_kernel(const float* __restrict__ hE, const float* __restrict__ cnt,
                            float* __restrict__ Hc, u64* deT) {
    const int i = blockIdx.x;     // one wave per row
    const int lane = threadIdx.x; // 64 threads
    float s = 0.f;
    for (int d = lane; d < MAXD; d += 64) {
        float v = hE[(size_t)i * MAXD + d];
        Hc[(size_t)i * MAXD + d] = v;
        s = fmaf(cnt[(size_t)i * MAXD + d], v, s);
    }
    #pragma unroll
    for (int off = 32; off; off >>= 1) s += __shfl_xor(s, off);
    if (lane == 0) {
        // epoch-0 data into slot 0 (tag field = 0)
        AT_STORE64(&deT[i], (u64)__float_as_uint(s / 1600.0f));
    }
}

__global__ __launch_bounds__(256) void dmf_main(
        const float* __restrict__ x0, const float* __restrict__ L,
        const float* __restrict__ theta, const float* __restrict__ noise,
        float* __restrict__ out, const float* __restrict__ cnt,
        float* __restrict__ Hc, u64* deT) {
    const int tid  = threadIdx.x;
    const int lane = tid & 63;
    const int wv   = tid >> 6;
    const int base = blockIdx.x * RPB + wv * RPW;   // first row of this wave

    const float std_in = theta[0],  W_E = theta[1],  tau_E = theta[2], gamma_E = theta[3];
    const float W_I = theta[4],     tau_I = theta[5], I_0 = theta[6],  g = theta[7];
    const float g_EE = theta[8],    g_IE = theta[9], g_EI = theta[10];
    const float aE = theta[11], bE = theta[12], dEc = theta[13];
    const float aI = theta[14], bI = theta[15], dIc = theta[16];
    const float sdt = std_in * sqrtf(DT);

    // lane r (r < RPW) owns row base+r
    float E = 0.f, I = 0.f, cnt0 = 0.f;
    float* Hmy = Hc;
    if (lane < RPW) {
        const int i = base + lane;
        E = x0[i * 2 + 0];
        I = x0[i * 2 + 1];
        cnt0 = cnt[(size_t)i * MAXD + 0];
        Hmy = Hc + (size_t)i * MAXD;
    }

    const float* Lr[RPW];
    const float* Hr[RPW];
    #pragma unroll
    for (int r = 0; r < RPW; ++r) {
        Lr[r] = L  + (size_t)(base + r) * NN;
        Hr[r] = Hc + (size_t)(base + r) * MAXD;
    }

    // delay-count weights in registers (fixed all run)
    float creg[8][RPW];
    #pragma unroll
    for (int k = 0; k < 8; ++k) {
        const int d = lane + k * 64;
        #pragma unroll
        for (int r = 0; r < RPW; ++r)
            creg[k][r] = (d < MAXD) ? cnt[(size_t)(base + r) * MAXD + d] : 0.f;
    }

    int h = 0;
    unsigned int e = 0;   // epoch

    for (int b = 0; b < NBATCH; ++b) {
        float nE = 0.f, nI = 0.f;
        if (lane < RPW) {
            const int i = base + lane;
            nE = noise[((size_t)b * NN + i) * 2 + 0] * sdt;
            nI = noise[((size_t)b * NN + i) * 2 + 1] * sdt;
            ((float2*)out)[(size_t)(b * TS) * NN + i] = make_float2(E, I);
        }

        for (int t = 1; t < TS; ++t) {
            h = (h == 0) ? (MAXD - 1) : (h - 1);   // new head (uniform)

            u64* src = deT + (size_t)(e & 1) * NN;
            u64* dst = deT + (size_t)((e + 1) & 1) * NN;

            // ---- issue all exchange-vector loads (latency hidden under 1b)
            u64 v[NN / 64];
            #pragma unroll
            for (int k = 0; k < NN / 64; ++k)
                v[k] = AT_LOAD64(&src[lane + k * 64]);

            // ---- phase 1b: delayed-sum over OLD history (d >= 1), purely local
            float s[RPW];
            #pragma unroll
            for (int r = 0; r < RPW; ++r) s[r] = 0.f;
            #pragma unroll
            for (int k = 0; k < 8; ++k) {
                const int d = lane + k * 64;
                if (d >= 1 && d < MAXD) {
                    int hd = h + d; if (hd >= MAXD) hd -= MAXD;
                    #pragma unroll
                    for (int r = 0; r < RPW; ++r) s[r] = fmaf(creg[k][r], Hr[r][hd], s[r]);
                }
            }

            // ---- tag fixup: re-poll any element not yet at this epoch
            #pragma unroll
            for (int k = 0; k < NN / 64; ++k) {
                while ((unsigned int)(v[k] >> 32) != e) {
                    __builtin_amdgcn_s_sleep(1);
                    v[k] = AT_LOAD64(&src[lane + k * 64]);
                }
            }

            // ---- matvec
            float p[RPW];
            #pragma unroll
            for (int r = 0; r < RPW; ++r) p[r] = 0.f;
            #pragma unroll
            for (int k = 0; k < NN / 64; ++k) {
                const int j = lane + k * 64;
                const float dv = __uint_as_float((unsigned int)v[k]);
                #pragma unroll
                for (int r = 0; r < RPW; ++r) p[r] = fmaf(Lr[r][j], dv, p[r]);
            }

            // ---- one butterfly for all 8 partials
            #pragma unroll
            for (int off = 32; off; off >>= 1) {
                #pragma unroll
                for (int r = 0; r < RPW; ++r) {
                    p[r] += __shfl_xor(p[r], off);
                    s[r] += __shfl_xor(s[r], off);
                }
            }
            float pv = p[0], sv = s[0];
            #pragma unroll
            for (int r = 1; r < RPW; ++r) {
                pv = (lane == r) ? p[r] : pv;
                sv = (lane == r) ? s[r] : sv;
            }

            // ---- per-row update in lane r, publish tagged delayed_E
            if (lane < RPW) {
                const float IE = W_E * I_0 + g_EE * E + g * pv - g_IE * I;
                const float II = W_I * I_0 + g_EI * E - I;
                const float RE = h_tf_dev(aE, bE, dEc, IE);
                const float RI = h_tf_dev(aI, bI, dIc, II);
                const float dEd = -E / tau_E + (1.0f - E) * gamma_E * RE;
                const float dId = -I / tau_I + RI;
                E = E + DT * dEd + nE;
                I = I + DT * dId + nI;
                Hmy[h] = E;                                   // push history
                const float sfin = (sv + cnt0 * E) * (1.0f / 1600.0f);
                AT_STORE64(&dst[base + lane],
                           (u64)__float_as_uint(sfin) | ((u64)(e + 1) << 32));
                ((float2*)out)[(size_t)(b * TS + t) * NN + (base + lane)] = make_float2(E, I);
            }
            ++e;
        }
    }

    // ---- finals: x_f then hE_f (logical order from circular buffer)
    const size_t xo = (size_t)(NBATCH * TS) * NN * 2;
    if (lane < RPW) {
        const int i = base + lane;
        ((float2*)out)[xo / 2 + i] = make_float2(E, I);
    }
    const size_t ho = xo + NN * 2;
    #pragma unroll
    for (int k = 0; k < 8; ++k) {
        const int d = lane + k * 64;
        if (d < MAXD) {
            int hd = h + d; if (hd >= MAXD) hd -= MAXD;
            #pragma unroll
            for (int r = 0; r < RPW; ++r)
                out[ho + (size_t)(base + r) * MAXD + d] = Hr[r][hd];
        }
    }
}

extern "C" void kernel_launch(void* const* d_in, const int* in_sizes, int n_in,
                              void* d_out, int out_size, void* d_ws, size_t ws_size,
                              hipStream_t stream) {
    const float* x0     = (const float*)d_in[0];
    const float* hE     = (const float*)d_in[1];
    const float* L      = (const float*)d_in[2];
    const float* theta  = (const float*)d_in[3];
    const float* noise  = (const float*)d_in[4];
    const int*   delays = (const int*)d_in[5];
    float* out = (float*)d_out;

    float* ws  = (float*)d_ws;
    float* cnt = ws;
    float* Hc  = ws + 800000;
    u64*   deT = (u64*)(ws + 1600000);

    cnt_kernel<<<NN, 256, 0, stream>>>(delays, cnt);
    init_kernel<<<NN, 64, 0, stream>>>(hE, cnt, Hc, deT);
    dmf_main<<<GBLK, 256, 0, stream>>>(x0, L, theta, noise, out, cnt, Hc, deT);
}